// Round 1
// baseline (1304.006 us; speedup 1.0000x reference)
//
#include <hip/hip_runtime.h>

typedef __bf16 bf16;
typedef bf16 bf16x4 __attribute__((ext_vector_type(4)));
typedef bf16 bf16x8 __attribute__((ext_vector_type(8)));
typedef float f32x4 __attribute__((ext_vector_type(4)));

#define B_  4
#define S_  2048
#define E_  1152
#define H_  12
#define D_  96
#define HD_ 1152      // H_*D_
#define M_  (B_*S_)   // 8192

// ---------------------------------------------------------------- cast fp32 -> bf16
__global__ __launch_bounds__(256) void cast_bf16_k(const float* __restrict__ in,
                                                   bf16* __restrict__ out) {
    size_t i = ((size_t)blockIdx.x * 256 + threadIdx.x) * 4;
    float4 v = *(const float4*)(in + i);
    bf16x4 o = { (bf16)v.x, (bf16)v.y, (bf16)v.z, (bf16)v.w };
    *(bf16x4*)(out + i) = o;
}

// ---------------------------------------------------------------- W [K x N] fp32 -> WT [N x K] bf16
__global__ __launch_bounds__(256) void transpose_w_k(const float* __restrict__ W,
                                                     bf16* __restrict__ WT) {
    __shared__ float t[32][33];
    int bx = blockIdx.x * 32;   // col block (n)
    int by = blockIdx.y * 32;   // row block (k)
    int tx = threadIdx.x, ty = threadIdx.y;
    #pragma unroll
    for (int i = ty; i < 32; i += 8)
        t[i][tx] = W[(size_t)(by + i) * E_ + bx + tx];
    __syncthreads();
    #pragma unroll
    for (int i = ty; i < 32; i += 8)
        WT[(size_t)(bx + i) * E_ + by + tx] = (bf16)t[tx][i];
}

// ---------------------------------------------------------------- v [B*S x HD] -> VT [(b*H+h)*D + d][s]
__global__ __launch_bounds__(256) void transpose_v_k(const bf16* __restrict__ v,
                                                     bf16* __restrict__ VT) {
    __shared__ bf16 t[32][33];
    int bh = blockIdx.z;
    int b = bh / H_, h = bh % H_;
    int s0 = blockIdx.x * 32, d0 = blockIdx.y * 32;
    int tx = threadIdx.x, ty = threadIdx.y;
    #pragma unroll
    for (int i = ty; i < 32; i += 8)
        t[i][tx] = v[(size_t)(b * S_ + s0 + i) * HD_ + h * D_ + d0 + tx];
    __syncthreads();
    #pragma unroll
    for (int i = ty; i < 32; i += 8)
        VT[(size_t)(bh * D_ + d0 + i) * S_ + s0 + tx] = t[tx][i];
}

// ---------------------------------------------------------------- RoPE in-place on [M_ x HD_] bf16
__global__ __launch_bounds__(256) void rope_k(bf16* __restrict__ x) {
    int idx = blockIdx.x * 256 + threadIdx.x;   // over M_ * (HD_/2)
    int row  = idx / (HD_ / 2);
    int pair = idx % (HD_ / 2);
    int s = row & (S_ - 1);
    int h = pair / (D_ / 2);
    int i = pair % (D_ / 2);
    float theta = powf(10000.0f, -(float)(2 * i) / 96.0f);
    float ang = (float)s * theta;
    float c = cosf(ang), sn = sinf(ang);
    size_t base = (size_t)row * HD_ + h * D_ + 2 * i;
    float x0 = (float)x[base], x1 = (float)x[base + 1];
    x[base]     = (bf16)(x0 * c - x1 * sn);
    x[base + 1] = (bf16)(x1 * c + x0 * sn);
}

// ---------------------------------------------------------------- GEMM: C[M x N] = X[M x K] * W[K x N] + bias
// WT is [N x K] bf16 (pre-transposed). Writes bf16 (Cb) or fp32 (Cf).
__global__ __launch_bounds__(256) void gemm_bf16_k(const bf16* __restrict__ X,
                                                   const bf16* __restrict__ WT,
                                                   const float* __restrict__ bias,
                                                   bf16* __restrict__ Cb,
                                                   float* __restrict__ Cf,
                                                   int M, int N, int K) {
    int wave = threadIdx.x >> 6;
    int lane = threadIdx.x & 63;
    int quad = lane >> 4;
    int l16  = lane & 15;
    int m0 = blockIdx.x * 64 + wave * 16;
    int n0 = blockIdx.y * 64;
    const bf16* xrow = X + (size_t)(m0 + l16) * K;
    const bf16* wrow = WT + (size_t)(n0 + l16) * K;

    f32x4 acc[4];
    #pragma unroll
    for (int t = 0; t < 4; ++t) acc[t] = (f32x4){0.f, 0.f, 0.f, 0.f};

    for (int k0 = 0; k0 < K; k0 += 32) {
        bf16x8 a = *(const bf16x8*)(xrow + k0 + quad * 8);
        #pragma unroll
        for (int t = 0; t < 4; ++t) {
            bf16x8 b = *(const bf16x8*)(wrow + (size_t)t * 16 * K + k0 + quad * 8);
            acc[t] = __builtin_amdgcn_mfma_f32_16x16x32_bf16(a, b, acc[t], 0, 0, 0);
        }
    }
    // C/D layout: row = quad*4 + r (m), col = l16 (n)
    if (Cf) {
        #pragma unroll
        for (int t = 0; t < 4; ++t) {
            int n = n0 + t * 16 + l16;
            float bv = bias[n];
            #pragma unroll
            for (int r = 0; r < 4; ++r)
                Cf[(size_t)(m0 + quad * 4 + r) * N + n] = acc[t][r] + bv;
        }
    } else {
        #pragma unroll
        for (int t = 0; t < 4; ++t) {
            int n = n0 + t * 16 + l16;
            float bv = bias[n];
            #pragma unroll
            for (int r = 0; r < 4; ++r)
                Cb[(size_t)(m0 + quad * 4 + r) * N + n] = (bf16)(acc[t][r] + bv);
        }
    }
}

// ---------------------------------------------------------------- flash attention
// Q,K: [B*S x HD] bf16 (roped). VT: [(b*H+h)*D + d][s] bf16. ctx: [B*S x HD] bf16.
__global__ __launch_bounds__(256) void flash_attn_k(const bf16* __restrict__ Q,
                                                    const bf16* __restrict__ K,
                                                    const bf16* __restrict__ VT,
                                                    bf16* __restrict__ ctx) {
    int wave = threadIdx.x >> 6;
    int lane = threadIdx.x & 63;
    int quad = lane >> 4;
    int l16  = lane & 15;
    int g  = blockIdx.x * 4 + wave;           // 0 .. B*H*(S/16)-1
    int bh = g % (B_ * H_);
    int qt = (S_ / 16 - 1) - g / (B_ * H_);   // heavy tiles first
    int b = bh / H_, h = bh % H_;
    int q0 = qt * 16;

    __shared__ bf16 Plds[4][16][32];

    const bf16* qrow = Q + (size_t)(b * S_ + q0 + l16) * HD_ + h * D_;
    bf16x8 qf[3];
    #pragma unroll
    for (int c = 0; c < 3; ++c)
        qf[c] = *(const bf16x8*)(qrow + c * 32 + quad * 8);

    f32x4 o[6];
    #pragma unroll
    for (int t = 0; t < 6; ++t) o[t] = (f32x4){0.f, 0.f, 0.f, 0.f};
    float mrow[4], lrow[4];
    #pragma unroll
    for (int r = 0; r < 4; ++r) { mrow[r] = -3.0e38f; lrow[r] = 0.f; }

    const float scale = 0.10206207261596575f;   // 1/sqrt(96)
    const float LOG2E = 1.4426950408889634f;
    int nk = ((q0 + 16 + 31) / 32) * 32;
    const bf16* Kbase = K + (size_t)(b * S_) * HD_ + h * D_;
    const bf16* Vbase = VT + (size_t)(bh * D_) * S_;

    for (int kb = 0; kb < nk; kb += 32) {
        f32x4 s0 = {0.f, 0.f, 0.f, 0.f}, s1 = {0.f, 0.f, 0.f, 0.f};
        const bf16* kr0 = Kbase + (size_t)(kb + l16) * HD_;
        const bf16* kr1 = Kbase + (size_t)(kb + 16 + l16) * HD_;
        #pragma unroll
        for (int c = 0; c < 3; ++c) {
            bf16x8 k0 = *(const bf16x8*)(kr0 + c * 32 + quad * 8);
            s0 = __builtin_amdgcn_mfma_f32_16x16x32_bf16(qf[c], k0, s0, 0, 0, 0);
            bf16x8 k1 = *(const bf16x8*)(kr1 + c * 32 + quad * 8);
            s1 = __builtin_amdgcn_mfma_f32_16x16x32_bf16(qf[c], k1, s1, 0, 0, 0);
        }
        float p0[4], p1[4];
        #pragma unroll
        for (int r = 0; r < 4; ++r) {
            int qi = q0 + quad * 4 + r;
            float v0 = (kb + l16      <= qi) ? s0[r] * scale : -3.0e38f;
            float v1 = (kb + 16 + l16 <= qi) ? s1[r] * scale : -3.0e38f;
            float mx = fmaxf(v0, v1);
            #pragma unroll
            for (int off = 8; off; off >>= 1)
                mx = fmaxf(mx, __shfl_xor(mx, off, 16));
            float mnew  = fmaxf(mrow[r], mx);
            float alpha = exp2f((mrow[r] - mnew) * LOG2E);
            float e0 = exp2f((v0 - mnew) * LOG2E);
            float e1 = exp2f((v1 - mnew) * LOG2E);
            float rs = e0 + e1;
            #pragma unroll
            for (int off = 8; off; off >>= 1)
                rs += __shfl_xor(rs, off, 16);
            lrow[r] = lrow[r] * alpha + rs;
            mrow[r] = mnew;
            #pragma unroll
            for (int t = 0; t < 6; ++t) o[t][r] *= alpha;
            p0[r] = e0; p1[r] = e1;
        }
        // C-layout -> A-layout via per-wave LDS
        #pragma unroll
        for (int r = 0; r < 4; ++r) {
            Plds[wave][quad * 4 + r][l16]      = (bf16)p0[r];
            Plds[wave][quad * 4 + r][l16 + 16] = (bf16)p1[r];
        }
        asm volatile("s_waitcnt lgkmcnt(0)" ::: "memory");
        bf16x8 pa = *(const bf16x8*)(&Plds[wave][l16][quad * 8]);
        #pragma unroll
        for (int t = 0; t < 6; ++t) {
            bf16x8 vf = *(const bf16x8*)(Vbase + (size_t)(t * 16 + l16) * S_ + kb + quad * 8);
            o[t] = __builtin_amdgcn_mfma_f32_16x16x32_bf16(pa, vf, o[t], 0, 0, 0);
        }
    }
    float inv[4];
    #pragma unroll
    for (int r = 0; r < 4; ++r) inv[r] = 1.0f / lrow[r];
    bf16* crow = ctx + (size_t)(b * S_ + q0) * HD_ + h * D_;
    #pragma unroll
    for (int t = 0; t < 6; ++t)
        #pragma unroll
        for (int r = 0; r < 4; ++r)
            crow[(size_t)(quad * 4 + r) * HD_ + t * 16 + l16] = (bf16)(o[t][r] * inv[r]);
}

// ---------------------------------------------------------------- launch
extern "C" void kernel_launch(void* const* d_in, const int* in_sizes, int n_in,
                              void* d_out, int out_size, void* d_ws, size_t ws_size,
                              hipStream_t stream) {
    const float* logits = (const float*)d_in[0];
    const float* Wq = (const float*)d_in[1];
    const float* bq = (const float*)d_in[2];
    const float* Wk = (const float*)d_in[3];
    const float* bk = (const float*)d_in[4];
    const float* Wv = (const float*)d_in[5];
    const float* bv = (const float*)d_in[6];
    const float* Wo = (const float*)d_in[7];
    const float* bo = (const float*)d_in[8];
    float* out = (float*)d_out;

    char* ws = (char*)d_ws;
    size_t off = 0;
    auto alloc = [&](size_t bytes) { char* p = ws + off; off += (bytes + 255) & ~(size_t)255; return p; };
    bf16* Xbf = (bf16*)alloc((size_t)M_ * E_ * 2);
    bf16* WqT = (bf16*)alloc((size_t)E_ * HD_ * 2);
    bf16* WkT = (bf16*)alloc((size_t)E_ * HD_ * 2);
    bf16* WvT = (bf16*)alloc((size_t)E_ * HD_ * 2);
    bf16* WoT = (bf16*)alloc((size_t)HD_ * E_ * 2);
    bf16* qb  = (bf16*)alloc((size_t)M_ * HD_ * 2);
    bf16* kb  = (bf16*)alloc((size_t)M_ * HD_ * 2);
    bf16* vb  = (bf16*)alloc((size_t)M_ * HD_ * 2);
    bf16* VT  = (bf16*)alloc((size_t)M_ * HD_ * 2);
    bf16* ctx = Xbf;  // reuse: logits-bf16 dead after QKV GEMMs

    // 1. cast logits
    hipLaunchKernelGGL(cast_bf16_k, dim3((M_ * (size_t)E_) / 1024), dim3(256), 0, stream, logits, Xbf);
    // 2. weight transposes
    hipLaunchKernelGGL(transpose_w_k, dim3(36, 36), dim3(32, 8), 0, stream, Wq, WqT);
    hipLaunchKernelGGL(transpose_w_k, dim3(36, 36), dim3(32, 8), 0, stream, Wk, WkT);
    hipLaunchKernelGGL(transpose_w_k, dim3(36, 36), dim3(32, 8), 0, stream, Wv, WvT);
    hipLaunchKernelGGL(transpose_w_k, dim3(36, 36), dim3(32, 8), 0, stream, Wo, WoT);
    // 3. QKV projections
    hipLaunchKernelGGL(gemm_bf16_k, dim3(M_ / 64, HD_ / 64), dim3(256), 0, stream, Xbf, WqT, bq, qb, (float*)nullptr, M_, HD_, E_);
    hipLaunchKernelGGL(gemm_bf16_k, dim3(M_ / 64, HD_ / 64), dim3(256), 0, stream, Xbf, WkT, bk, kb, (float*)nullptr, M_, HD_, E_);
    hipLaunchKernelGGL(gemm_bf16_k, dim3(M_ / 64, HD_ / 64), dim3(256), 0, stream, Xbf, WvT, bv, vb, (float*)nullptr, M_, HD_, E_);
    // 4. RoPE on q, k
    hipLaunchKernelGGL(rope_k, dim3((M_ * (HD_ / 2)) / 256), dim3(256), 0, stream, qb);
    hipLaunchKernelGGL(rope_k, dim3((M_ * (HD_ / 2)) / 256), dim3(256), 0, stream, kb);
    // 5. V transpose
    hipLaunchKernelGGL(transpose_v_k, dim3(S_ / 32, D_ / 32, B_ * H_), dim3(32, 8), 0, stream, vb, VT);
    // 6. flash attention
    hipLaunchKernelGGL(flash_attn_k, dim3(B_ * H_ * (S_ / 16) / 4), dim3(256), 0, stream, qb, kb, VT, ctx);
    // 7. output projection (fp32 out)
    hipLaunchKernelGGL(gemm_bf16_k, dim3(M_ / 64, E_ / 64), dim3(256), 0, stream, ctx, WoT, bo, (bf16*)nullptr, out, M_, E_, HD_);
}

// Round 2
// 454.090 us; speedup vs baseline: 2.8717x; 2.8717x over previous
//
#include <hip/hip_runtime.h>

typedef __bf16 bf16;
typedef bf16 bf16x4 __attribute__((ext_vector_type(4)));
typedef bf16 bf16x8 __attribute__((ext_vector_type(8)));
typedef float f32x4 __attribute__((ext_vector_type(4)));

#define B_  4
#define S_  2048
#define E_  1152
#define H_  12
#define D_  96
#define HD_ 1152      // H_*D_
#define M_  (B_*S_)   // 8192
#define BH_ (B_*H_)   // 48

__device__ __forceinline__ void gl2lds16(const void* g, void* l) {
    __builtin_amdgcn_global_load_lds((const __attribute__((address_space(1))) void*)g,
                                     (__attribute__((address_space(3))) void*)l, 16, 0, 0);
}

// ---------------------------------------------------------------- cast fp32 -> bf16
__global__ __launch_bounds__(256) void cast_bf16_k(const float* __restrict__ in,
                                                   bf16* __restrict__ out) {
    size_t i = ((size_t)blockIdx.x * 256 + threadIdx.x) * 4;
    float4 v = *(const float4*)(in + i);
    bf16x4 o = { (bf16)v.x, (bf16)v.y, (bf16)v.z, (bf16)v.w };
    *(bf16x4*)(out + i) = o;
}

// ---------------------------------------------------------------- W [K x N] fp32 -> WT [N x K] bf16
__global__ __launch_bounds__(256) void transpose_w_k(const float* __restrict__ W,
                                                     bf16* __restrict__ WT) {
    __shared__ float t[32][33];
    int bx = blockIdx.x * 32;   // col block (n)
    int by = blockIdx.y * 32;   // row block (k)
    int tx = threadIdx.x, ty = threadIdx.y;
    #pragma unroll
    for (int i = ty; i < 32; i += 8)
        t[i][tx] = W[(size_t)(by + i) * E_ + bx + tx];
    __syncthreads();
    #pragma unroll
    for (int i = ty; i < 32; i += 8)
        WT[(size_t)(bx + i) * E_ + by + tx] = (bf16)t[tx][i];
}

// ---------------------------------------------------------------- v [B*S x HD] -> VT [(b*H+h)*D + d][s]
__global__ __launch_bounds__(256) void transpose_v_k(const bf16* __restrict__ v,
                                                     bf16* __restrict__ VT) {
    __shared__ bf16 t[32][33];
    int bh = blockIdx.z;
    int b = bh / H_, h = bh % H_;
    int s0 = blockIdx.x * 32, d0 = blockIdx.y * 32;
    int tx = threadIdx.x, ty = threadIdx.y;
    #pragma unroll
    for (int i = ty; i < 32; i += 8)
        t[i][tx] = v[(size_t)(b * S_ + s0 + i) * HD_ + h * D_ + d0 + tx];
    __syncthreads();
    #pragma unroll
    for (int i = ty; i < 32; i += 8)
        VT[(size_t)(bh * D_ + d0 + i) * S_ + s0 + tx] = t[tx][i];
}

// ---------------------------------------------------------------- RoPE in-place on [M_ x HD_] bf16
__global__ __launch_bounds__(256) void rope_k(bf16* __restrict__ x) {
    int idx = blockIdx.x * 256 + threadIdx.x;   // over M_ * (HD_/2)
    int row  = idx / (HD_ / 2);
    int pair = idx % (HD_ / 2);
    int s = row & (S_ - 1);
    int h = pair / (D_ / 2);
    int i = pair % (D_ / 2);
    float theta = powf(10000.0f, -(float)(2 * i) / 96.0f);
    float ang = (float)s * theta;
    float c = cosf(ang), sn = sinf(ang);
    size_t base = (size_t)row * HD_ + h * D_ + 2 * i;
    float x0 = (float)x[base], x1 = (float)x[base + 1];
    x[base]     = (bf16)(x0 * c - x1 * sn);
    x[base + 1] = (bf16)(x1 * c + x0 * sn);
}

// ---------------------------------------------------------------- m97-style 128x128 GEMM body
// C[8192 x 1152] = X[8192 x K] * WT^T (WT is [1152 x K] bf16) + bias
__device__ __forceinline__ void gemm128_body(const bf16* __restrict__ X,
                                             const bf16* __restrict__ WT,
                                             const float* __restrict__ bias,
                                             bf16* __restrict__ Cb,
                                             float* __restrict__ Cf,
                                             int K) {
    __shared__ bf16 As[128 * 32];
    __shared__ bf16 Bs[128 * 32];
    const int N = 1152;
    int t = threadIdx.x;
    int lane = t & 63, wave = t >> 6;
    int quad = lane >> 4, l16 = lane & 15;
    int wm = wave >> 1, wn = wave & 1;
    int m0 = blockIdx.x * 128, n0 = blockIdx.y * 128;

    const bf16* ga = X  + (size_t)(m0 + (t >> 2)) * K + (t & 3) * 8;
    const bf16* gb = WT + (size_t)(n0 + (t >> 2)) * K + (t & 3) * 8;
    bf16* la = As + t * 8;
    bf16* lb = Bs + t * 8;
    size_t rowskip = (size_t)64 * K;

    f32x4 acc[4][4];
    #pragma unroll
    for (int u = 0; u < 4; ++u)
        #pragma unroll
        for (int v = 0; v < 4; ++v) acc[u][v] = (f32x4){0.f, 0.f, 0.f, 0.f};

    for (int k0 = 0; k0 < K; k0 += 32) {
        __syncthreads();
        gl2lds16(ga + k0,           la);
        gl2lds16(ga + k0 + rowskip, la + 64 * 32);
        gl2lds16(gb + k0,           lb);
        gl2lds16(gb + k0 + rowskip, lb + 64 * 32);
        __syncthreads();
        bf16x8 af[4], bfr[4];
        #pragma unroll
        for (int u = 0; u < 4; ++u)
            af[u] = *(const bf16x8*)(As + (wm * 64 + u * 16 + l16) * 32 + quad * 8);
        #pragma unroll
        for (int v = 0; v < 4; ++v)
            bfr[v] = *(const bf16x8*)(Bs + (wn * 64 + v * 16 + l16) * 32 + quad * 8);
        #pragma unroll
        for (int u = 0; u < 4; ++u)
            #pragma unroll
            for (int v = 0; v < 4; ++v)
                acc[u][v] = __builtin_amdgcn_mfma_f32_16x16x32_bf16(af[u], bfr[v], acc[u][v], 0, 0, 0);
    }

    int mrow = m0 + wm * 64, ncol = n0 + wn * 64;
    if (Cf) {
        #pragma unroll
        for (int v = 0; v < 4; ++v) {
            int n = ncol + v * 16 + l16;
            float bv = bias[n];
            #pragma unroll
            for (int u = 0; u < 4; ++u)
                #pragma unroll
                for (int r = 0; r < 4; ++r)
                    Cf[(size_t)(mrow + u * 16 + quad * 4 + r) * N + n] = acc[u][v][r] + bv;
        }
    } else {
        #pragma unroll
        for (int v = 0; v < 4; ++v) {
            int n = ncol + v * 16 + l16;
            float bv = bias[n];
            #pragma unroll
            for (int u = 0; u < 4; ++u)
                #pragma unroll
                for (int r = 0; r < 4; ++r)
                    Cb[(size_t)(mrow + u * 16 + quad * 4 + r) * N + n] = (bf16)(acc[u][v][r] + bv);
        }
    }
}

__global__ __launch_bounds__(256) void gemm_qkv_k(const bf16* __restrict__ X,
        const bf16* __restrict__ Wq, const bf16* __restrict__ Wk, const bf16* __restrict__ Wv,
        const float* __restrict__ bq, const float* __restrict__ bk, const float* __restrict__ bv,
        bf16* __restrict__ q, bf16* __restrict__ k, bf16* __restrict__ v) {
    const bf16* W; const float* bias; bf16* C;
    if (blockIdx.z == 0)      { W = Wq; bias = bq; C = q; }
    else if (blockIdx.z == 1) { W = Wk; bias = bk; C = k; }
    else                      { W = Wv; bias = bv; C = v; }
    gemm128_body(X, W, bias, C, nullptr, E_);
}

__global__ __launch_bounds__(256) void gemm_out_k(const bf16* __restrict__ X,
        const bf16* __restrict__ WT, const float* __restrict__ bias, float* __restrict__ Cf) {
    gemm128_body(X, WT, bias, nullptr, Cf, HD_);
}

// ---------------------------------------------------------------- flash attention, block-cooperative
// One block = one (b,h) x 64 q-rows. K-tile 64x96 + VT-tile 96x(64+8) staged in LDS.
__global__ __launch_bounds__(256) void flash2_k(const bf16* __restrict__ Q,
                                                const bf16* __restrict__ Kg,
                                                const bf16* __restrict__ VT,
                                                bf16* __restrict__ ctx) {
    __shared__ bf16 Ks[64 * 96];        // [s][d]       12288 B
    __shared__ bf16 Vs[96 * 72];        // [d][s+pad]   13824 B
    __shared__ bf16 Ps[4][16][72];      // per-wave P    9216 B
    int t = threadIdx.x, lane = t & 63, wave = t >> 6;
    int quad = lane >> 4, l16 = lane & 15;
    int bh = blockIdx.x % BH_;
    int ch = (S_ / 64 - 1) - blockIdx.x / BH_;   // heavy chunks first
    int b = bh / H_, h = bh % H_;
    int q0 = ch * 64;
    int qw = q0 + wave * 16;

    const char* Kbase = (const char*)(Kg + (size_t)(b * S_) * HD_ + h * D_);
    const char* Vbase = (const char*)(VT + (size_t)(bh * D_) * S_);

    // staging maps: Ks = 768 16B-chunks (12/row); Vs = 864 chunks (9/row, chunk 8 = pad)
    int kr[3], kc[3], vr[4], vc[4];
    #pragma unroll
    for (int i = 0; i < 3; ++i) { int c = i * 256 + t; kr[i] = c / 12; kc[i] = c % 12; }
    #pragma unroll
    for (int i = 0; i < 4; ++i) { int c = i * 256 + t; vr[i] = c / 9; int cc = c % 9; vc[i] = (cc == 8) ? 7 : cc; }

    const bf16* qrow = Q + (size_t)(b * S_ + qw + l16) * HD_ + h * D_;
    bf16x8 qf[3];
    #pragma unroll
    for (int c = 0; c < 3; ++c)
        qf[c] = *(const bf16x8*)(qrow + c * 32 + quad * 8);

    f32x4 o[6];
    #pragma unroll
    for (int u = 0; u < 6; ++u) o[u] = (f32x4){0.f, 0.f, 0.f, 0.f};
    float mrow[4], lrow[4];
    #pragma unroll
    for (int r = 0; r < 4; ++r) { mrow[r] = -3.0e38f; lrow[r] = 0.f; }

    const float scale = 0.10206207261596575f;   // 1/sqrt(96)
    const float LOG2E = 1.4426950408889634f;
    int nk = q0 + 64;

    for (int kb = 0; kb < nk; kb += 64) {
        __syncthreads();
        const char* kg = Kbase + (size_t)kb * (HD_ * 2);
        #pragma unroll
        for (int i = 0; i < 3; ++i)
            gl2lds16(kg + (size_t)kr[i] * (HD_ * 2) + kc[i] * 16, (char*)Ks + i * 4096 + t * 16);
        #pragma unroll
        for (int i = 0; i < 4; ++i)
            if (i < 3 || t < 96)
                gl2lds16(Vbase + (size_t)vr[i] * (S_ * 2) + kb * 2 + vc[i] * 16,
                         (char*)Vs + i * 4096 + t * 16);
        __syncthreads();

        // QK^T: 16 q-rows x 64 k-cols per wave
        f32x4 s[4];
        #pragma unroll
        for (int u = 0; u < 4; ++u) s[u] = (f32x4){0.f, 0.f, 0.f, 0.f};
        #pragma unroll
        for (int c = 0; c < 3; ++c) {
            #pragma unroll
            for (int u = 0; u < 4; ++u) {
                bf16x8 kf = *(const bf16x8*)(Ks + (u * 16 + l16) * 96 + c * 32 + quad * 8);
                s[u] = __builtin_amdgcn_mfma_f32_16x16x32_bf16(qf[c], kf, s[u], 0, 0, 0);
            }
        }

        // online softmax over the 64 cols
        #pragma unroll
        for (int r = 0; r < 4; ++r) {
            int qi = qw + quad * 4 + r;
            float v0 = (kb      + l16 <= qi) ? s[0][r] * scale : -3.0e38f;
            float v1 = (kb + 16 + l16 <= qi) ? s[1][r] * scale : -3.0e38f;
            float v2 = (kb + 32 + l16 <= qi) ? s[2][r] * scale : -3.0e38f;
            float v3 = (kb + 48 + l16 <= qi) ? s[3][r] * scale : -3.0e38f;
            float mx = fmaxf(fmaxf(v0, v1), fmaxf(v2, v3));
            #pragma unroll
            for (int off = 8; off; off >>= 1)
                mx = fmaxf(mx, __shfl_xor(mx, off, 16));
            float mnew  = fmaxf(mrow[r], mx);
            float alpha = exp2f((mrow[r] - mnew) * LOG2E);
            float e0 = exp2f((v0 - mnew) * LOG2E);
            float e1 = exp2f((v1 - mnew) * LOG2E);
            float e2 = exp2f((v2 - mnew) * LOG2E);
            float e3 = exp2f((v3 - mnew) * LOG2E);
            float rs = e0 + e1 + e2 + e3;
            #pragma unroll
            for (int off = 8; off; off >>= 1)
                rs += __shfl_xor(rs, off, 16);
            lrow[r] = lrow[r] * alpha + rs;
            mrow[r] = mnew;
            #pragma unroll
            for (int u = 0; u < 6; ++u) o[u][r] *= alpha;
            Ps[wave][quad * 4 + r][l16]      = (bf16)e0;
            Ps[wave][quad * 4 + r][l16 + 16] = (bf16)e1;
            Ps[wave][quad * 4 + r][l16 + 32] = (bf16)e2;
            Ps[wave][quad * 4 + r][l16 + 48] = (bf16)e3;
        }
        asm volatile("s_waitcnt lgkmcnt(0)" ::: "memory");

        // PV: P[16x64] @ V[64x96]
        bf16x8 pa0 = *(const bf16x8*)(&Ps[wave][l16][quad * 8]);
        bf16x8 pa1 = *(const bf16x8*)(&Ps[wave][l16][32 + quad * 8]);
        #pragma unroll
        for (int u = 0; u < 6; ++u) {
            bf16x8 vf0 = *(const bf16x8*)(Vs + (u * 16 + l16) * 72 + quad * 8);
            o[u] = __builtin_amdgcn_mfma_f32_16x16x32_bf16(pa0, vf0, o[u], 0, 0, 0);
            bf16x8 vf1 = *(const bf16x8*)(Vs + (u * 16 + l16) * 72 + 32 + quad * 8);
            o[u] = __builtin_amdgcn_mfma_f32_16x16x32_bf16(pa1, vf1, o[u], 0, 0, 0);
        }
    }

    float inv[4];
    #pragma unroll
    for (int r = 0; r < 4; ++r) inv[r] = 1.0f / lrow[r];
    bf16* crow = ctx + (size_t)(b * S_ + qw) * HD_ + h * D_;
    #pragma unroll
    for (int u = 0; u < 6; ++u)
        #pragma unroll
        for (int r = 0; r < 4; ++r)
            crow[(size_t)(quad * 4 + r) * HD_ + u * 16 + l16] = (bf16)(o[u][r] * inv[r]);
}

// ---------------------------------------------------------------- launch
extern "C" void kernel_launch(void* const* d_in, const int* in_sizes, int n_in,
                              void* d_out, int out_size, void* d_ws, size_t ws_size,
                              hipStream_t stream) {
    const float* logits = (const float*)d_in[0];
    const float* Wq = (const float*)d_in[1];
    const float* bq = (const float*)d_in[2];
    const float* Wk = (const float*)d_in[3];
    const float* bk = (const float*)d_in[4];
    const float* Wv = (const float*)d_in[5];
    const float* bv = (const float*)d_in[6];
    const float* Wo = (const float*)d_in[7];
    const float* bo = (const float*)d_in[8];
    float* out = (float*)d_out;

    char* ws = (char*)d_ws;
    size_t off = 0;
    auto alloc = [&](size_t bytes) { char* p = ws + off; off += (bytes + 255) & ~(size_t)255; return p; };
    bf16* Xbf = (bf16*)alloc((size_t)M_ * E_ * 2);
    bf16* WqT = (bf16*)alloc((size_t)E_ * HD_ * 2);
    bf16* WkT = (bf16*)alloc((size_t)E_ * HD_ * 2);
    bf16* WvT = (bf16*)alloc((size_t)E_ * HD_ * 2);
    bf16* WoT = (bf16*)alloc((size_t)HD_ * E_ * 2);
    bf16* qb  = (bf16*)alloc((size_t)M_ * HD_ * 2);
    bf16* kb  = (bf16*)alloc((size_t)M_ * HD_ * 2);
    bf16* vb  = (bf16*)alloc((size_t)M_ * HD_ * 2);
    bf16* VT  = (bf16*)alloc((size_t)M_ * HD_ * 2);
    bf16* ctx = Xbf;  // reuse: logits-bf16 dead after QKV GEMMs

    hipLaunchKernelGGL(cast_bf16_k, dim3((M_ * (size_t)E_) / 1024), dim3(256), 0, stream, logits, Xbf);
    hipLaunchKernelGGL(transpose_w_k, dim3(36, 36), dim3(32, 8), 0, stream, Wq, WqT);
    hipLaunchKernelGGL(transpose_w_k, dim3(36, 36), dim3(32, 8), 0, stream, Wk, WkT);
    hipLaunchKernelGGL(transpose_w_k, dim3(36, 36), dim3(32, 8), 0, stream, Wv, WvT);
    hipLaunchKernelGGL(transpose_w_k, dim3(36, 36), dim3(32, 8), 0, stream, Wo, WoT);
    hipLaunchKernelGGL(gemm_qkv_k, dim3(M_ / 128, 1152 / 128, 3), dim3(256), 0, stream,
                       Xbf, WqT, WkT, WvT, bq, bk, bv, qb, kb, vb);
    hipLaunchKernelGGL(rope_k, dim3((M_ * (HD_ / 2)) / 256), dim3(256), 0, stream, qb);
    hipLaunchKernelGGL(rope_k, dim3((M_ * (HD_ / 2)) / 256), dim3(256), 0, stream, kb);
    hipLaunchKernelGGL(transpose_v_k, dim3(S_ / 32, D_ / 32, BH_), dim3(32, 8), 0, stream, vb, VT);
    hipLaunchKernelGGL(flash2_k, dim3(BH_ * (S_ / 64)), dim3(256), 0, stream, qb, kb, VT, ctx);
    hipLaunchKernelGGL(gemm_out_k, dim3(M_ / 128, 1152 / 128), dim3(256), 0, stream, ctx, WoT, bo, out);
}

// Round 4
// 367.550 us; speedup vs baseline: 3.5478x; 1.2355x over previous
//
#include <hip/hip_runtime.h>

typedef __bf16 bf16;
typedef bf16 bf16x4 __attribute__((ext_vector_type(4)));
typedef bf16 bf16x8 __attribute__((ext_vector_type(8)));
typedef float f32x4 __attribute__((ext_vector_type(4)));

#define B_  4
#define S_  2048
#define E_  1152
#define H_  12
#define D_  96
#define HD_ 1152      // H_*D_
#define M_  (B_*S_)   // 8192
#define BH_ (B_*H_)   // 48

__device__ __forceinline__ void gl2lds16(const void* g, void* l) {
    __builtin_amdgcn_global_load_lds((const __attribute__((address_space(1))) void*)g,
                                     (__attribute__((address_space(3))) void*)l, 16, 0, 0);
}

// ---------------------------------------------------------------- cast fp32 -> bf16
__global__ __launch_bounds__(256) void cast_bf16_k(const float* __restrict__ in,
                                                   bf16* __restrict__ out) {
    size_t i = ((size_t)blockIdx.x * 256 + threadIdx.x) * 4;
    float4 v = *(const float4*)(in + i);
    bf16x4 o = { (bf16)v.x, (bf16)v.y, (bf16)v.z, (bf16)v.w };
    *(bf16x4*)(out + i) = o;
}

// ---------------------------------------------------------------- RoPE cos/sin table [S_][48] (accurate libm)
__global__ __launch_bounds__(256) void rope_tab_k(float2* __restrict__ tab) {
    int idx = blockIdx.x * 256 + threadIdx.x;   // S_*48
    int s = idx / 48, i = idx % 48;
    float theta = powf(10000.0f, -(float)(2 * i) / 96.0f);
    float ang = (float)s * theta;
    tab[idx] = make_float2(cosf(ang), sinf(ang));
}

// ---------------------------------------------------------------- 4x W [K x N] fp32 -> WT [N x K] bf16 (one launch)
__global__ __launch_bounds__(256) void transpose_w_all_k(const float* __restrict__ W0,
        const float* __restrict__ W1, const float* __restrict__ W2, const float* __restrict__ W3,
        bf16* __restrict__ T0, bf16* __restrict__ T1, bf16* __restrict__ T2, bf16* __restrict__ T3) {
    const float* W; bf16* WT;
    switch (blockIdx.z) {
        case 0: W = W0; WT = T0; break;
        case 1: W = W1; WT = T1; break;
        case 2: W = W2; WT = T2; break;
        default: W = W3; WT = T3; break;
    }
    __shared__ float t[32][33];
    int bx = blockIdx.x * 32;   // col block (n)
    int by = blockIdx.y * 32;   // row block (k)
    int tx = threadIdx.x, ty = threadIdx.y;
    #pragma unroll
    for (int i = ty; i < 32; i += 8)
        t[i][tx] = W[(size_t)(by + i) * E_ + bx + tx];
    __syncthreads();
    #pragma unroll
    for (int i = ty; i < 32; i += 8)
        WT[(size_t)(bx + i) * E_ + by + tx] = (bf16)t[tx][i];
}

// ---------------------------------------------------------------- v [B*S x HD] -> VT [(b*H+h)*D + d][s]
__global__ __launch_bounds__(256) void transpose_v_k(const bf16* __restrict__ v,
                                                     bf16* __restrict__ VT) {
    __shared__ bf16 t[32][33];
    int bh = blockIdx.z;
    int b = bh / H_, h = bh % H_;
    int s0 = blockIdx.x * 32, d0 = blockIdx.y * 32;
    int tx = threadIdx.x, ty = threadIdx.y;
    #pragma unroll
    for (int i = ty; i < 32; i += 8)
        t[i][tx] = v[(size_t)(b * S_ + s0 + i) * HD_ + h * D_ + d0 + tx];
    __syncthreads();
    #pragma unroll
    for (int i = ty; i < 32; i += 8)
        VT[(size_t)(bh * D_ + d0 + i) * S_ + s0 + tx] = t[tx][i];
}

// ---------------------------------------------------------------- m97-style 128x128 GEMM body (+optional fused RoPE)
__device__ __forceinline__ void gemm128_body(const bf16* __restrict__ X,
                                             const bf16* __restrict__ WT,
                                             const float* __restrict__ bias,
                                             bf16* __restrict__ Cb,
                                             float* __restrict__ Cf,
                                             const float2* __restrict__ ctab,
                                             int K, int rope) {
    __shared__ bf16 As[128 * 32];
    __shared__ bf16 Bs[128 * 32];
    const int N = 1152;
    int t = threadIdx.x;
    int lane = t & 63, wave = t >> 6;
    int quad = lane >> 4, l16 = lane & 15;
    int wm = wave >> 1, wn = wave & 1;
    int m0 = blockIdx.x * 128, n0 = blockIdx.y * 128;

    const bf16* ga = X  + (size_t)(m0 + (t >> 2)) * K + (t & 3) * 8;
    const bf16* gb = WT + (size_t)(n0 + (t >> 2)) * K + (t & 3) * 8;
    bf16* la = As + t * 8;
    bf16* lb = Bs + t * 8;
    size_t rowskip = (size_t)64 * K;

    f32x4 acc[4][4];
    #pragma unroll
    for (int u = 0; u < 4; ++u)
        #pragma unroll
        for (int v = 0; v < 4; ++v) acc[u][v] = (f32x4){0.f, 0.f, 0.f, 0.f};

    for (int k0 = 0; k0 < K; k0 += 32) {
        __syncthreads();
        gl2lds16(ga + k0,           la);
        gl2lds16(ga + k0 + rowskip, la + 64 * 32);
        gl2lds16(gb + k0,           lb);
        gl2lds16(gb + k0 + rowskip, lb + 64 * 32);
        __syncthreads();
        bf16x8 af[4], bfr[4];
        #pragma unroll
        for (int u = 0; u < 4; ++u)
            af[u] = *(const bf16x8*)(As + (wm * 64 + u * 16 + l16) * 32 + quad * 8);
        #pragma unroll
        for (int v = 0; v < 4; ++v)
            bfr[v] = *(const bf16x8*)(Bs + (wn * 64 + v * 16 + l16) * 32 + quad * 8);
        #pragma unroll
        for (int u = 0; u < 4; ++u)
            #pragma unroll
            for (int v = 0; v < 4; ++v)
                acc[u][v] = __builtin_amdgcn_mfma_f32_16x16x32_bf16(af[u], bfr[v], acc[u][v], 0, 0, 0);
    }

    int mrow = m0 + wm * 64, ncol = n0 + wn * 64;
    if (Cf) {
        #pragma unroll
        for (int v = 0; v < 4; ++v) {
            int n = ncol + v * 16 + l16;
            float bv = bias[n];
            #pragma unroll
            for (int u = 0; u < 4; ++u)
                #pragma unroll
                for (int r = 0; r < 4; ++r)
                    Cf[(size_t)(mrow + u * 16 + quad * 4 + r) * N + n] = acc[u][v][r] + bv;
        }
    } else if (rope) {
        #pragma unroll
        for (int v = 0; v < 4; ++v) {
            int n = ncol + v * 16 + l16;
            float bv = bias[n];
            int i = (n % 96) >> 1;
            float sgn = (n & 1) ? 1.f : -1.f;
            #pragma unroll
            for (int u = 0; u < 4; ++u)
                #pragma unroll
                for (int r = 0; r < 4; ++r) {
                    int m = mrow + u * 16 + quad * 4 + r;
                    float x = acc[u][v][r] + bv;
                    float p = __shfl_xor(x, 1, 64);   // partner channel (n^1), same row
                    float2 cs = ctab[(m & (S_ - 1)) * 48 + i];
                    Cb[(size_t)m * N + n] = (bf16)(x * cs.x + p * sgn * cs.y);
                }
        }
    } else {
        #pragma unroll
        for (int v = 0; v < 4; ++v) {
            int n = ncol + v * 16 + l16;
            float bv = bias[n];
            #pragma unroll
            for (int u = 0; u < 4; ++u)
                #pragma unroll
                for (int r = 0; r < 4; ++r)
                    Cb[(size_t)(mrow + u * 16 + quad * 4 + r) * N + n] = (bf16)(acc[u][v][r] + bv);
        }
    }
}

__global__ __launch_bounds__(256) void gemm_qkv_k(const bf16* __restrict__ X,
        const bf16* __restrict__ Wq, const bf16* __restrict__ Wk, const bf16* __restrict__ Wv,
        const float* __restrict__ bq, const float* __restrict__ bk, const float* __restrict__ bv,
        bf16* __restrict__ q, bf16* __restrict__ k, bf16* __restrict__ v,
        const float2* __restrict__ ctab) {
    const bf16* W; const float* bias; bf16* C; int rope;
    if (blockIdx.z == 0)      { W = Wq; bias = bq; C = q; rope = 1; }
    else if (blockIdx.z == 1) { W = Wk; bias = bk; C = k; rope = 1; }
    else                      { W = Wv; bias = bv; C = v; rope = 0; }
    gemm128_body(X, W, bias, C, nullptr, ctab, E_, rope);
}

__global__ __launch_bounds__(256) void gemm_out_k(const bf16* __restrict__ X,
        const bf16* __restrict__ WT, const float* __restrict__ bias, float* __restrict__ Cf) {
    gemm128_body(X, WT, bias, nullptr, Cf, nullptr, HD_, 0);
}

// ---------------------------------------------------------------- flash attention v3b
// S^T = K.Q^T so each lane's column is a fixed q: per-lane softmax, fixed shift
// (safe: |score| <= |q||k|/sqrt(96) << 88). lsum is a 1/4-partial sum per lane
// (lane holds rows quad*4+r only) -> cross-quad allreduce ONCE after the loop.
// PV swapped: O^T = V^T . P^T; output col = q = l16.
__global__ __launch_bounds__(256) void flash3_k(const bf16* __restrict__ Q,
                                                const bf16* __restrict__ Kg,
                                                const bf16* __restrict__ VT,
                                                bf16* __restrict__ ctx) {
    __shared__ bf16 Ks[64 * 104];       // [s][d], rows padded 96->104 (2-way banks)
    __shared__ bf16 Vs[96 * 72];        // [d][s+pad]
    __shared__ bf16 Ps[4][16][72];      // per-wave P[q][s]
    int t = threadIdx.x, lane = t & 63, wave = t >> 6;
    int quad = lane >> 4, l16 = lane & 15;
    int bh = blockIdx.x % BH_;
    int ch = (S_ / 64 - 1) - blockIdx.x / BH_;   // heavy chunks first
    int b = bh / H_, h = bh % H_;
    int q0 = ch * 64;
    int qw = q0 + wave * 16;
    int qabs = qw + l16;

    const char* KbaseB = (const char*)(Kg + (size_t)(b * S_) * HD_ + h * D_);
    const char* VbaseB = (const char*)(VT + (size_t)(bh * D_) * S_);

    // staging maps: Ks = 832 16B-chunks (13/row incl 1 pad); Vs = 864 (9/row, chunk8 = pad dup)
    int krow[4], koff[4], vrow[4], voff[4];
    #pragma unroll
    for (int i = 0; i < 4; ++i) {
        int c = i * 256 + t;
        krow[i] = c / 13; koff[i] = (c % 13) * 16;
        vrow[i] = c / 9;  int cc = c % 9; voff[i] = ((cc == 8) ? 7 : cc) * 16;
    }

    const bf16* qrow = Q + (size_t)(b * S_ + qw + l16) * HD_ + h * D_;
    bf16x8 qf[3];
    #pragma unroll
    for (int c = 0; c < 3; ++c)
        qf[c] = *(const bf16x8*)(qrow + c * 32 + quad * 8);

    f32x4 o[6];
    #pragma unroll
    for (int u = 0; u < 6; ++u) o[u] = (f32x4){0.f, 0.f, 0.f, 0.f};
    float lsum = 0.f;
    const float K2 = 0.10206207261596575f * 1.4426950408889634f;  // scale*log2(e)
    int nk = q0 + 64;

    for (int kb = 0; kb < nk; kb += 64) {
        __syncthreads();
        const char* kg = KbaseB + (size_t)kb * (HD_ * 2);
        #pragma unroll
        for (int i = 0; i < 3; ++i)
            gl2lds16(kg + (size_t)krow[i] * (HD_ * 2) + koff[i], (char*)Ks + i * 4096 + t * 16);
        if (t < 64)
            gl2lds16(kg + (size_t)krow[3] * (HD_ * 2) + koff[3], (char*)Ks + 12288 + t * 16);
        #pragma unroll
        for (int i = 0; i < 4; ++i)
            if (i < 3 || t < 96)
                gl2lds16(VbaseB + (size_t)vrow[i] * (S_ * 2) + (size_t)kb * 2 + voff[i],
                         (char*)Vs + i * 4096 + t * 16);
        __syncthreads();

        // S^T[s][q]: A = K-tile rows (s), B = Q rows (q)
        f32x4 st[4];
        #pragma unroll
        for (int u = 0; u < 4; ++u) st[u] = (f32x4){0.f, 0.f, 0.f, 0.f};
        #pragma unroll
        for (int c = 0; c < 3; ++c)
            #pragma unroll
            for (int u = 0; u < 4; ++u) {
                bf16x8 kf = *(const bf16x8*)(Ks + (u * 16 + l16) * 104 + c * 32 + quad * 8);
                st[u] = __builtin_amdgcn_mfma_f32_16x16x32_bf16(kf, qf[c], st[u], 0, 0, 0);
            }

        // per-lane softmax (q = l16 fixed): no shuffles, no rescale
        #pragma unroll
        for (int u = 0; u < 4; ++u) {
            bf16x4 pv;
            #pragma unroll
            for (int r = 0; r < 4; ++r) {
                int sidx = kb + u * 16 + quad * 4 + r;
                float e = __builtin_exp2f(st[u][r] * K2);
                e = (sidx <= qabs) ? e : 0.f;
                lsum += e;
                pv[r] = (bf16)e;
            }
            *(bf16x4*)(&Ps[wave][l16][u * 16 + quad * 4]) = pv;   // b64 packed write
        }
        asm volatile("s_waitcnt lgkmcnt(0)" ::: "memory");

        // O^T += V^T . P^T : A = Vs rows (d), B = Ps rows (q)
        bf16x8 p0 = *(const bf16x8*)(&Ps[wave][l16][quad * 8]);
        bf16x8 p1 = *(const bf16x8*)(&Ps[wave][l16][32 + quad * 8]);
        #pragma unroll
        for (int u = 0; u < 6; ++u) {
            bf16x8 v0 = *(const bf16x8*)(Vs + (u * 16 + l16) * 72 + quad * 8);
            o[u] = __builtin_amdgcn_mfma_f32_16x16x32_bf16(v0, p0, o[u], 0, 0, 0);
            bf16x8 v1 = *(const bf16x8*)(Vs + (u * 16 + l16) * 72 + 32 + quad * 8);
            o[u] = __builtin_amdgcn_mfma_f32_16x16x32_bf16(v1, p1, o[u], 0, 0, 0);
        }
    }

    // cross-quad allreduce of the denominator (lanes l16+{0,16,32,48} share q)
    lsum += __shfl_xor(lsum, 16, 64);
    lsum += __shfl_xor(lsum, 32, 64);
    float inv = 1.0f / lsum;

    bf16* crow = ctx + (size_t)(b * S_ + qw + l16) * HD_ + h * D_;
    #pragma unroll
    for (int u = 0; u < 6; ++u) {
        bf16x4 ov;
        #pragma unroll
        for (int r = 0; r < 4; ++r) ov[r] = (bf16)(o[u][r] * inv);
        *(bf16x4*)(crow + u * 16 + quad * 4) = ov;   // b64 packed store
    }
}

// ---------------------------------------------------------------- launch
extern "C" void kernel_launch(void* const* d_in, const int* in_sizes, int n_in,
                              void* d_out, int out_size, void* d_ws, size_t ws_size,
                              hipStream_t stream) {
    const float* logits = (const float*)d_in[0];
    const float* Wq = (const float*)d_in[1];
    const float* bq = (const float*)d_in[2];
    const float* Wk = (const float*)d_in[3];
    const float* bk = (const float*)d_in[4];
    const float* Wv = (const float*)d_in[5];
    const float* bv = (const float*)d_in[6];
    const float* Wo = (const float*)d_in[7];
    const float* bo = (const float*)d_in[8];
    float* out = (float*)d_out;

    char* ws = (char*)d_ws;
    size_t off = 0;
    auto alloc = [&](size_t bytes) { char* p = ws + off; off += (bytes + 255) & ~(size_t)255; return p; };
    bf16* Xbf = (bf16*)alloc((size_t)M_ * E_ * 2);
    bf16* WqT = (bf16*)alloc((size_t)E_ * HD_ * 2);
    bf16* WkT = (bf16*)alloc((size_t)E_ * HD_ * 2);
    bf16* WvT = (bf16*)alloc((size_t)E_ * HD_ * 2);
    bf16* WoT = (bf16*)alloc((size_t)HD_ * E_ * 2);
    bf16* qb  = (bf16*)alloc((size_t)M_ * HD_ * 2);
    bf16* kb  = (bf16*)alloc((size_t)M_ * HD_ * 2);
    bf16* vb  = (bf16*)alloc((size_t)M_ * HD_ * 2);
    bf16* VT  = (bf16*)alloc((size_t)M_ * HD_ * 2);
    float2* ctab = (float2*)alloc((size_t)S_ * 48 * 8);
    bf16* ctx = Xbf;  // reuse: logits-bf16 dead after QKV GEMMs

    hipLaunchKernelGGL(cast_bf16_k, dim3((M_ * (size_t)E_) / 1024), dim3(256), 0, stream, logits, Xbf);
    hipLaunchKernelGGL(rope_tab_k, dim3((S_ * 48) / 256), dim3(256), 0, stream, ctab);
    hipLaunchKernelGGL(transpose_w_all_k, dim3(36, 36, 4), dim3(32, 8), 0, stream,
                       Wq, Wk, Wv, Wo, WqT, WkT, WvT, WoT);
    hipLaunchKernelGGL(gemm_qkv_k, dim3(M_ / 128, 1152 / 128, 3), dim3(256), 0, stream,
                       Xbf, WqT, WkT, WvT, bq, bk, bv, qb, kb, vb, ctab);
    hipLaunchKernelGGL(transpose_v_k, dim3(S_ / 32, D_ / 32, BH_), dim3(32, 8), 0, stream, vb, VT);
    hipLaunchKernelGGL(flash3_k, dim3(BH_ * (S_ / 64)), dim3(256), 0, stream, qb, kb, VT, ctx);
    hipLaunchKernelGGL(gemm_out_k, dim3(M_ / 128, 1152 / 128), dim3(256), 0, stream, ctx, WoT, bo, out);
}

// Round 5
// 342.307 us; speedup vs baseline: 3.8095x; 1.0737x over previous
//
#include <hip/hip_runtime.h>

typedef __bf16 bf16;
typedef bf16 bf16x4 __attribute__((ext_vector_type(4)));
typedef bf16 bf16x8 __attribute__((ext_vector_type(8)));
typedef float f32x4 __attribute__((ext_vector_type(4)));

#define B_  4
#define S_  2048
#define E_  1152
#define H_  12
#define D_  96
#define HD_ 1152      // H_*D_
#define M_  (B_*S_)   // 8192
#define BH_ (B_*H_)   // 48

__device__ __forceinline__ void gl2lds16(const void* g, void* l) {
    __builtin_amdgcn_global_load_lds((const __attribute__((address_space(1))) void*)g,
                                     (__attribute__((address_space(3))) void*)l, 16, 0, 0);
}

// ---------------------------------------------------------------- cast fp32 -> bf16
__global__ __launch_bounds__(256) void cast_bf16_k(const float* __restrict__ in,
                                                   bf16* __restrict__ out) {
    size_t i = ((size_t)blockIdx.x * 256 + threadIdx.x) * 4;
    float4 v = *(const float4*)(in + i);
    bf16x4 o = { (bf16)v.x, (bf16)v.y, (bf16)v.z, (bf16)v.w };
    *(bf16x4*)(out + i) = o;
}

// ---------------------------------------------------------------- RoPE cos/sin table [S_][48] (accurate libm)
__global__ __launch_bounds__(256) void rope_tab_k(float2* __restrict__ tab) {
    int idx = blockIdx.x * 256 + threadIdx.x;   // S_*48
    int s = idx / 48, i = idx % 48;
    float theta = powf(10000.0f, -(float)(2 * i) / 96.0f);
    float ang = (float)s * theta;
    tab[idx] = make_float2(cosf(ang), sinf(ang));
}

// ---------------------------------------------------------------- 4x W [K x N] fp32 -> WT [N x K] bf16 (one launch)
__global__ __launch_bounds__(256) void transpose_w_all_k(const float* __restrict__ W0,
        const float* __restrict__ W1, const float* __restrict__ W2, const float* __restrict__ W3,
        bf16* __restrict__ T0, bf16* __restrict__ T1, bf16* __restrict__ T2, bf16* __restrict__ T3) {
    const float* W; bf16* WT;
    switch (blockIdx.z) {
        case 0: W = W0; WT = T0; break;
        case 1: W = W1; WT = T1; break;
        case 2: W = W2; WT = T2; break;
        default: W = W3; WT = T3; break;
    }
    __shared__ float t[32][33];
    int bx = blockIdx.x * 32;   // col block (n)
    int by = blockIdx.y * 32;   // row block (k)
    int tx = threadIdx.x, ty = threadIdx.y;
    #pragma unroll
    for (int i = ty; i < 32; i += 8)
        t[i][tx] = W[(size_t)(by + i) * E_ + bx + tx];
    __syncthreads();
    #pragma unroll
    for (int i = ty; i < 32; i += 8)
        WT[(size_t)(bx + i) * E_ + by + tx] = (bf16)t[tx][i];
}

// ---------------------------------------------------------------- v [B*S x HD] -> VT [(b*H+h)*D + d][s]
__global__ __launch_bounds__(256) void transpose_v_k(const bf16* __restrict__ v,
                                                     bf16* __restrict__ VT) {
    __shared__ bf16 t[32][33];
    int bh = blockIdx.z;
    int b = bh / H_, h = bh % H_;
    int s0 = blockIdx.x * 32, d0 = blockIdx.y * 32;
    int tx = threadIdx.x, ty = threadIdx.y;
    #pragma unroll
    for (int i = ty; i < 32; i += 8)
        t[i][tx] = v[(size_t)(b * S_ + s0 + i) * HD_ + h * D_ + d0 + tx];
    __syncthreads();
    #pragma unroll
    for (int i = ty; i < 32; i += 8)
        VT[(size_t)(bh * D_ + d0 + i) * S_ + s0 + tx] = t[tx][i];
}

// ---------------------------------------------------------------- 128x128 GEMM body, BK=64, XOR-swizzled LDS
// LDS slot (row, c') holds global chunk (row, c' ^ (row&7)); ds_read applies the
// same XOR -> 2-way banks (free) instead of 8/16-way. BK=64 halves barrier count.
__device__ __forceinline__ void gemm128_body(const bf16* __restrict__ X,
                                             const bf16* __restrict__ WT,
                                             const float* __restrict__ bias,
                                             bf16* __restrict__ Cb,
                                             float* __restrict__ Cf,
                                             const float2* __restrict__ ctab,
                                             int K, int rope, int m0, int n0) {
    __shared__ bf16 As[128 * 64];
    __shared__ bf16 Bs[128 * 64];
    const int N = 1152;
    int t = threadIdx.x;
    int lane = t & 63, wave = t >> 6;
    int quad = lane >> 4, l16 = lane & 15;
    int wm = wave >> 1, wn = wave & 1;

    // staging: 1024 chunks of 16B per tile; thread t, instr i -> slot i*256+t
    int srow = t >> 3;                              // 0..31 (+ i*32)
    int scol = ((t & 7) ^ (srow & 7)) * 8;          // swizzled global col (elements)
    const bf16* ga = X  + (size_t)(m0 + srow) * K + scol;
    const bf16* gb = WT + (size_t)(n0 + srow) * K + scol;
    bf16* la = As + t * 8;
    bf16* lb = Bs + t * 8;
    size_t skip = (size_t)32 * K;

    f32x4 acc[4][4];
    #pragma unroll
    for (int u = 0; u < 4; ++u)
        #pragma unroll
        for (int v = 0; v < 4; ++v) acc[u][v] = (f32x4){0.f, 0.f, 0.f, 0.f};

    for (int k0 = 0; k0 < K; k0 += 64) {
        __syncthreads();
        #pragma unroll
        for (int i = 0; i < 4; ++i) {
            gl2lds16(ga + k0 + i * skip, la + i * 2048);
            gl2lds16(gb + k0 + i * skip, lb + i * 2048);
        }
        __syncthreads();
        #pragma unroll
        for (int kk = 0; kk < 2; ++kk) {
            int xc = ((kk * 4 + quad) ^ (l16 & 7)) * 8;   // swizzled chunk offset (el)
            bf16x8 af[4], bfr[4];
            #pragma unroll
            for (int u = 0; u < 4; ++u)
                af[u] = *(const bf16x8*)(As + (wm * 64 + u * 16 + l16) * 64 + xc);
            #pragma unroll
            for (int v = 0; v < 4; ++v)
                bfr[v] = *(const bf16x8*)(Bs + (wn * 64 + v * 16 + l16) * 64 + xc);
            #pragma unroll
            for (int u = 0; u < 4; ++u)
                #pragma unroll
                for (int v = 0; v < 4; ++v)
                    acc[u][v] = __builtin_amdgcn_mfma_f32_16x16x32_bf16(af[u], bfr[v], acc[u][v], 0, 0, 0);
        }
    }

    int mrow = m0 + wm * 64, ncol = n0 + wn * 64;
    if (Cf) {
        #pragma unroll
        for (int v = 0; v < 4; ++v) {
            int n = ncol + v * 16 + l16;
            float bv = bias[n];
            #pragma unroll
            for (int u = 0; u < 4; ++u)
                #pragma unroll
                for (int r = 0; r < 4; ++r)
                    Cf[(size_t)(mrow + u * 16 + quad * 4 + r) * N + n] = acc[u][v][r] + bv;
        }
    } else if (rope) {
        #pragma unroll
        for (int v = 0; v < 4; ++v) {
            int n = ncol + v * 16 + l16;
            float bv = bias[n];
            int i = (n % 96) >> 1;
            float sgn = (n & 1) ? 1.f : -1.f;
            #pragma unroll
            for (int u = 0; u < 4; ++u)
                #pragma unroll
                for (int r = 0; r < 4; ++r) {
                    int m = mrow + u * 16 + quad * 4 + r;
                    float x = acc[u][v][r] + bv;
                    float p = __shfl_xor(x, 1, 64);   // partner channel (n^1), same row
                    float2 cs = ctab[(m & (S_ - 1)) * 48 + i];
                    Cb[(size_t)m * N + n] = (bf16)(x * cs.x + p * sgn * cs.y);
                }
        }
    } else {
        #pragma unroll
        for (int v = 0; v < 4; ++v) {
            int n = ncol + v * 16 + l16;
            float bv = bias[n];
            #pragma unroll
            for (int u = 0; u < 4; ++u)
                #pragma unroll
                for (int r = 0; r < 4; ++r)
                    Cb[(size_t)(mrow + u * 16 + quad * 4 + r) * N + n] = (bf16)(acc[u][v][r] + bv);
        }
    }
}

// fused QKV: grid (64, 27); zone = y/9 selects q/k/v
__global__ __launch_bounds__(256) void gemm_qkv_k(const bf16* __restrict__ X,
        const bf16* __restrict__ Wq, const bf16* __restrict__ Wk, const bf16* __restrict__ Wv,
        const float* __restrict__ bq, const float* __restrict__ bk, const float* __restrict__ bv,
        bf16* __restrict__ q, bf16* __restrict__ k, bf16* __restrict__ v,
        const float2* __restrict__ ctab) {
    int zone = blockIdx.y / 9;
    int n0 = (blockIdx.y % 9) * 128;
    const bf16* W; const float* bias; bf16* C; int rope;
    if (zone == 0)      { W = Wq; bias = bq; C = q; rope = 1; }
    else if (zone == 1) { W = Wk; bias = bk; C = k; rope = 1; }
    else                { W = Wv; bias = bv; C = v; rope = 0; }
    gemm128_body(X, W, bias, C, nullptr, ctab, E_, rope, blockIdx.x * 128, n0);
}

__global__ __launch_bounds__(256) void gemm_out_k(const bf16* __restrict__ X,
        const bf16* __restrict__ WT, const float* __restrict__ bias, float* __restrict__ Cf) {
    gemm128_body(X, WT, bias, nullptr, Cf, nullptr, HD_, 0, blockIdx.x * 128, blockIdx.y * 128);
}

// ---------------------------------------------------------------- flash attention v3b
// S^T = K.Q^T so each lane's column is a fixed q: per-lane softmax, fixed shift
// (safe: |score| <= |q||k|/sqrt(96) << 88). lsum is a 1/4-partial sum per lane
// -> cross-quad allreduce ONCE after the loop. O^T = V^T . P^T; output col = q.
__global__ __launch_bounds__(256) void flash3_k(const bf16* __restrict__ Q,
                                                const bf16* __restrict__ Kg,
                                                const bf16* __restrict__ VT,
                                                bf16* __restrict__ ctx) {
    __shared__ bf16 Ks[64 * 104];       // [s][d], rows padded 96->104 (2-way banks)
    __shared__ bf16 Vs[96 * 72];        // [d][s+pad]
    __shared__ bf16 Ps[4][16][72];      // per-wave P[q][s]
    int t = threadIdx.x, lane = t & 63, wave = t >> 6;
    int quad = lane >> 4, l16 = lane & 15;
    int bh = blockIdx.x % BH_;
    int ch = (S_ / 64 - 1) - blockIdx.x / BH_;   // heavy chunks first
    int b = bh / H_, h = bh % H_;
    int q0 = ch * 64;
    int qw = q0 + wave * 16;
    int qabs = qw + l16;

    const char* KbaseB = (const char*)(Kg + (size_t)(b * S_) * HD_ + h * D_);
    const char* VbaseB = (const char*)(VT + (size_t)(bh * D_) * S_);

    int krow[4], koff[4], vrow[4], voff[4];
    #pragma unroll
    for (int i = 0; i < 4; ++i) {
        int c = i * 256 + t;
        krow[i] = c / 13; koff[i] = (c % 13) * 16;
        vrow[i] = c / 9;  int cc = c % 9; voff[i] = ((cc == 8) ? 7 : cc) * 16;
    }

    const bf16* qrow = Q + (size_t)(b * S_ + qw + l16) * HD_ + h * D_;
    bf16x8 qf[3];
    #pragma unroll
    for (int c = 0; c < 3; ++c)
        qf[c] = *(const bf16x8*)(qrow + c * 32 + quad * 8);

    f32x4 o[6];
    #pragma unroll
    for (int u = 0; u < 6; ++u) o[u] = (f32x4){0.f, 0.f, 0.f, 0.f};
    float lsum = 0.f;
    const float K2 = 0.10206207261596575f * 1.4426950408889634f;  // scale*log2(e)
    int nk = q0 + 64;

    for (int kb = 0; kb < nk; kb += 64) {
        __syncthreads();
        const char* kg = KbaseB + (size_t)kb * (HD_ * 2);
        #pragma unroll
        for (int i = 0; i < 3; ++i)
            gl2lds16(kg + (size_t)krow[i] * (HD_ * 2) + koff[i], (char*)Ks + i * 4096 + t * 16);
        if (t < 64)
            gl2lds16(kg + (size_t)krow[3] * (HD_ * 2) + koff[3], (char*)Ks + 12288 + t * 16);
        #pragma unroll
        for (int i = 0; i < 4; ++i)
            if (i < 3 || t < 96)
                gl2lds16(VbaseB + (size_t)vrow[i] * (S_ * 2) + (size_t)kb * 2 + voff[i],
                         (char*)Vs + i * 4096 + t * 16);
        __syncthreads();

        f32x4 st[4];
        #pragma unroll
        for (int u = 0; u < 4; ++u) st[u] = (f32x4){0.f, 0.f, 0.f, 0.f};
        #pragma unroll
        for (int c = 0; c < 3; ++c)
            #pragma unroll
            for (int u = 0; u < 4; ++u) {
                bf16x8 kf = *(const bf16x8*)(Ks + (u * 16 + l16) * 104 + c * 32 + quad * 8);
                st[u] = __builtin_amdgcn_mfma_f32_16x16x32_bf16(kf, qf[c], st[u], 0, 0, 0);
            }

        #pragma unroll
        for (int u = 0; u < 4; ++u) {
            bf16x4 pv;
            #pragma unroll
            for (int r = 0; r < 4; ++r) {
                int sidx = kb + u * 16 + quad * 4 + r;
                float e = __builtin_exp2f(st[u][r] * K2);
                e = (sidx <= qabs) ? e : 0.f;
                lsum += e;
                pv[r] = (bf16)e;
            }
            *(bf16x4*)(&Ps[wave][l16][u * 16 + quad * 4]) = pv;
        }
        asm volatile("s_waitcnt lgkmcnt(0)" ::: "memory");

        bf16x8 p0 = *(const bf16x8*)(&Ps[wave][l16][quad * 8]);
        bf16x8 p1 = *(const bf16x8*)(&Ps[wave][l16][32 + quad * 8]);
        #pragma unroll
        for (int u = 0; u < 6; ++u) {
            bf16x8 v0 = *(const bf16x8*)(Vs + (u * 16 + l16) * 72 + quad * 8);
            o[u] = __builtin_amdgcn_mfma_f32_16x16x32_bf16(v0, p0, o[u], 0, 0, 0);
            bf16x8 v1 = *(const bf16x8*)(Vs + (u * 16 + l16) * 72 + 32 + quad * 8);
            o[u] = __builtin_amdgcn_mfma_f32_16x16x32_bf16(v1, p1, o[u], 0, 0, 0);
        }
    }

    lsum += __shfl_xor(lsum, 16, 64);
    lsum += __shfl_xor(lsum, 32, 64);
    float inv = 1.0f / lsum;

    bf16* crow = ctx + (size_t)(b * S_ + qw + l16) * HD_ + h * D_;
    #pragma unroll
    for (int u = 0; u < 6; ++u) {
        bf16x4 ov;
        #pragma unroll
        for (int r = 0; r < 4; ++r) ov[r] = (bf16)(o[u][r] * inv);
        *(bf16x4*)(crow + u * 16 + quad * 4) = ov;
    }
}

// ---------------------------------------------------------------- launch
extern "C" void kernel_launch(void* const* d_in, const int* in_sizes, int n_in,
                              void* d_out, int out_size, void* d_ws, size_t ws_size,
                              hipStream_t stream) {
    const float* logits = (const float*)d_in[0];
    const float* Wq = (const float*)d_in[1];
    const float* bq = (const float*)d_in[2];
    const float* Wk = (const float*)d_in[3];
    const float* bk = (const float*)d_in[4];
    const float* Wv = (const float*)d_in[5];
    const float* bv = (const float*)d_in[6];
    const float* Wo = (const float*)d_in[7];
    const float* bo = (const float*)d_in[8];
    float* out = (float*)d_out;

    char* ws = (char*)d_ws;
    size_t off = 0;
    auto alloc = [&](size_t bytes) { char* p = ws + off; off += (bytes + 255) & ~(size_t)255; return p; };
    bf16* Xbf = (bf16*)alloc((size_t)M_ * E_ * 2);
    bf16* WqT = (bf16*)alloc((size_t)E_ * HD_ * 2);
    bf16* WkT = (bf16*)alloc((size_t)E_ * HD_ * 2);
    bf16* WvT = (bf16*)alloc((size_t)E_ * HD_ * 2);
    bf16* WoT = (bf16*)alloc((size_t)HD_ * E_ * 2);
    bf16* qb  = (bf16*)alloc((size_t)M_ * HD_ * 2);
    bf16* kb  = (bf16*)alloc((size_t)M_ * HD_ * 2);
    bf16* vb  = (bf16*)alloc((size_t)M_ * HD_ * 2);
    bf16* VT  = (bf16*)alloc((size_t)M_ * HD_ * 2);
    float2* ctab = (float2*)alloc((size_t)S_ * 48 * 8);
    bf16* ctx = Xbf;  // reuse: logits-bf16 dead after QKV GEMMs

    hipLaunchKernelGGL(cast_bf16_k, dim3((M_ * (size_t)E_) / 1024), dim3(256), 0, stream, logits, Xbf);
    hipLaunchKernelGGL(rope_tab_k, dim3((S_ * 48) / 256), dim3(256), 0, stream, ctab);
    hipLaunchKernelGGL(transpose_w_all_k, dim3(36, 36, 4), dim3(32, 8), 0, stream,
                       Wq, Wk, Wv, Wo, WqT, WkT, WvT, WoT);
    hipLaunchKernelGGL(gemm_qkv_k, dim3(M_ / 128, 27), dim3(256), 0, stream,
                       Xbf, WqT, WkT, WvT, bq, bk, bv, qb, kb, vb, ctab);
    hipLaunchKernelGGL(transpose_v_k, dim3(S_ / 32, D_ / 32, BH_), dim3(32, 8), 0, stream, vb, VT);
    hipLaunchKernelGGL(flash3_k, dim3(BH_ * (S_ / 64)), dim3(256), 0, stream, qb, kb, VT, ctx);
    hipLaunchKernelGGL(gemm_out_k, dim3(M_ / 128, 1152 / 128), dim3(256), 0, stream, ctx, WoT, bo, out);
}

// Round 6
// 329.578 us; speedup vs baseline: 3.9566x; 1.0386x over previous
//
#include <hip/hip_runtime.h>

typedef __bf16 bf16;
typedef bf16 bf16x4 __attribute__((ext_vector_type(4)));
typedef bf16 bf16x8 __attribute__((ext_vector_type(8)));
typedef float f32x4 __attribute__((ext_vector_type(4)));

#define B_  4
#define S_  2048
#define E_  1152
#define H_  12
#define D_  96
#define HD_ 1152      // H_*D_
#define M_  (B_*S_)   // 8192
#define BH_ (B_*H_)   // 48

__device__ __forceinline__ void gl2lds16(const void* g, void* l) {
    __builtin_amdgcn_global_load_lds((const __attribute__((address_space(1))) void*)g,
                                     (__attribute__((address_space(3))) void*)l, 16, 0, 0);
}

// ---------------------------------------------------------------- fused prep:
// [0,9216): cast logits fp32->bf16 ; [9216,9600): rope table ; [9600,14784): 4x W transpose
#define CAST_B_ 9216
#define TAB_B_  384
__global__ __launch_bounds__(256) void prep_k(const float* __restrict__ logits,
        bf16* __restrict__ Xbf, float2* __restrict__ ctab,
        const float* __restrict__ W0, const float* __restrict__ W1,
        const float* __restrict__ W2, const float* __restrict__ W3,
        bf16* __restrict__ T0, bf16* __restrict__ T1,
        bf16* __restrict__ T2, bf16* __restrict__ T3) {
    __shared__ float tsm[32][33];
    int bid = blockIdx.x, t = threadIdx.x;
    if (bid < CAST_B_) {
        size_t i = ((size_t)bid * 256 + t) * 4;
        float4 v = *(const float4*)(logits + i);
        bf16x4 o = { (bf16)v.x, (bf16)v.y, (bf16)v.z, (bf16)v.w };
        *(bf16x4*)(Xbf + i) = o;
    } else if (bid < CAST_B_ + TAB_B_) {
        int idx = (bid - CAST_B_) * 256 + t;
        int s = idx / 48, i = idx % 48;
        float theta = powf(10000.0f, -(float)(2 * i) / 96.0f);
        float ang = (float)s * theta;
        ctab[idx] = make_float2(cosf(ang), sinf(ang));
    } else {
        int tw = bid - (CAST_B_ + TAB_B_);
        int z = tw / 1296, rem = tw % 1296;
        const float* W; bf16* WT;
        switch (z) {
            case 0: W = W0; WT = T0; break;
            case 1: W = W1; WT = T1; break;
            case 2: W = W2; WT = T2; break;
            default: W = W3; WT = T3; break;
        }
        int bx = (rem % 36) * 32, by = (rem / 36) * 32;
        int tx = t & 31, ty = t >> 5;
        #pragma unroll
        for (int i = ty; i < 32; i += 8)
            tsm[i][tx] = W[(size_t)(by + i) * E_ + bx + tx];
        __syncthreads();
        #pragma unroll
        for (int i = ty; i < 32; i += 8)
            WT[(size_t)(bx + i) * E_ + by + tx] = (bf16)tsm[tx][i];
    }
}

// ---------------------------------------------------------------- 128x128 GEMM body, BK=64, XOR-swizzled LDS
// mode: 0 = bf16 C, 1 = bf16 C + fused RoPE, 2 = write transposed VT[(b*12+h)*96+d][s], 3 = fp32 C
__device__ __forceinline__ void gemm128_body(const bf16* __restrict__ X,
                                             const bf16* __restrict__ WT,
                                             const float* __restrict__ bias,
                                             bf16* __restrict__ Cb,
                                             float* __restrict__ Cf,
                                             const float2* __restrict__ ctab,
                                             int K, int mode, int m0, int n0) {
    __shared__ bf16 As[128 * 64];
    __shared__ bf16 Bs[128 * 64];
    const int N = 1152;
    int t = threadIdx.x;
    int lane = t & 63, wave = t >> 6;
    int quad = lane >> 4, l16 = lane & 15;
    int wm = wave >> 1, wn = wave & 1;

    int srow = t >> 3;
    int scol = ((t & 7) ^ (srow & 7)) * 8;
    const bf16* ga = X  + (size_t)(m0 + srow) * K + scol;
    const bf16* gb = WT + (size_t)(n0 + srow) * K + scol;
    bf16* la = As + t * 8;
    bf16* lb = Bs + t * 8;
    size_t skip = (size_t)32 * K;

    f32x4 acc[4][4];
    #pragma unroll
    for (int u = 0; u < 4; ++u)
        #pragma unroll
        for (int v = 0; v < 4; ++v) acc[u][v] = (f32x4){0.f, 0.f, 0.f, 0.f};

    for (int k0 = 0; k0 < K; k0 += 64) {
        __syncthreads();
        #pragma unroll
        for (int i = 0; i < 4; ++i) {
            gl2lds16(ga + k0 + i * skip, la + i * 2048);
            gl2lds16(gb + k0 + i * skip, lb + i * 2048);
        }
        __syncthreads();
        #pragma unroll
        for (int kk = 0; kk < 2; ++kk) {
            int xc = ((kk * 4 + quad) ^ (l16 & 7)) * 8;
            bf16x8 af[4], bfr[4];
            #pragma unroll
            for (int u = 0; u < 4; ++u)
                af[u] = *(const bf16x8*)(As + (wm * 64 + u * 16 + l16) * 64 + xc);
            #pragma unroll
            for (int v = 0; v < 4; ++v)
                bfr[v] = *(const bf16x8*)(Bs + (wn * 64 + v * 16 + l16) * 64 + xc);
            #pragma unroll
            for (int u = 0; u < 4; ++u)
                #pragma unroll
                for (int v = 0; v < 4; ++v)
                    acc[u][v] = __builtin_amdgcn_mfma_f32_16x16x32_bf16(af[u], bfr[v], acc[u][v], 0, 0, 0);
        }
    }

    int mrow = m0 + wm * 64, ncol = n0 + wn * 64;
    if (mode == 3) {
        #pragma unroll
        for (int v = 0; v < 4; ++v) {
            int n = ncol + v * 16 + l16;
            float bv = bias[n];
            #pragma unroll
            for (int u = 0; u < 4; ++u)
                #pragma unroll
                for (int r = 0; r < 4; ++r)
                    Cf[(size_t)(mrow + u * 16 + quad * 4 + r) * N + n] = acc[u][v][r] + bv;
        }
    } else if (mode == 1) {
        #pragma unroll
        for (int v = 0; v < 4; ++v) {
            int n = ncol + v * 16 + l16;
            float bv = bias[n];
            int i = (n % 96) >> 1;
            float sgn = (n & 1) ? 1.f : -1.f;
            #pragma unroll
            for (int u = 0; u < 4; ++u)
                #pragma unroll
                for (int r = 0; r < 4; ++r) {
                    int m = mrow + u * 16 + quad * 4 + r;
                    float x = acc[u][v][r] + bv;
                    float p = __shfl_xor(x, 1, 64);
                    float2 cs = ctab[(m & (S_ - 1)) * 48 + i];
                    Cb[(size_t)m * N + n] = (bf16)(x * cs.x + p * sgn * cs.y);
                }
        }
    } else if (mode == 2) {
        int bbase = (mrow >> 11) * H_;     // b*12 (block never straddles b)
        #pragma unroll
        for (int v = 0; v < 4; ++v) {
            int n = ncol + v * 16 + l16;
            int h = n / 96, d = n % 96;
            float bv = bias[n];
            bf16* vt = Cb + (size_t)((bbase + h) * 96 + d) * S_;
            #pragma unroll
            for (int u = 0; u < 4; ++u) {
                int s = (mrow + u * 16 + quad * 4) & (S_ - 1);
                bf16x4 val;
                #pragma unroll
                for (int r = 0; r < 4; ++r) val[r] = (bf16)(acc[u][v][r] + bv);
                *(bf16x4*)(vt + s) = val;   // b64 store, 4 consecutive s at fixed d
            }
        }
    } else {
        #pragma unroll
        for (int v = 0; v < 4; ++v) {
            int n = ncol + v * 16 + l16;
            float bv = bias[n];
            #pragma unroll
            for (int u = 0; u < 4; ++u)
                #pragma unroll
                for (int r = 0; r < 4; ++r)
                    Cb[(size_t)(mrow + u * 16 + quad * 4 + r) * N + n] = (bf16)(acc[u][v][r] + bv);
        }
    }
}

// fused QKV: grid (64, 27); zone = y/9 selects q/k/v. v-zone writes VT directly.
__global__ __launch_bounds__(256) void gemm_qkv_k(const bf16* __restrict__ X,
        const bf16* __restrict__ Wq, const bf16* __restrict__ Wk, const bf16* __restrict__ Wv,
        const float* __restrict__ bq, const float* __restrict__ bk, const float* __restrict__ bv,
        bf16* __restrict__ q, bf16* __restrict__ k, bf16* __restrict__ vt,
        const float2* __restrict__ ctab) {
    int zone = blockIdx.y / 9;
    int n0 = (blockIdx.y % 9) * 128;
    const bf16* W; const float* bias; bf16* C; int mode;
    if (zone == 0)      { W = Wq; bias = bq; C = q;  mode = 1; }
    else if (zone == 1) { W = Wk; bias = bk; C = k;  mode = 1; }
    else                { W = Wv; bias = bv; C = vt; mode = 2; }
    gemm128_body(X, W, bias, C, nullptr, ctab, E_, mode, blockIdx.x * 128, n0);
}

__global__ __launch_bounds__(256) void gemm_out_k(const bf16* __restrict__ X,
        const bf16* __restrict__ WT, const float* __restrict__ bias, float* __restrict__ Cf) {
    gemm128_body(X, WT, bias, nullptr, Cf, nullptr, HD_, 3, blockIdx.x * 128, blockIdx.y * 128);
}

// ---------------------------------------------------------------- flash attention v4
// Block = 128 q-rows of one (b,h); wave = 32 q (two 16-col B-fragment groups) so
// K/V LDS fragments amortize over 2x MFMAs. S^T = K.Q^T (per-lane softmax, fixed
// shift); O^T = V^T.P^T. lsum partial per lane -> cross-quad allreduce at end.
__global__ __launch_bounds__(256) void flash4_k(const bf16* __restrict__ Q,
                                                const bf16* __restrict__ Kg,
                                                const bf16* __restrict__ VT,
                                                bf16* __restrict__ ctx) {
    __shared__ bf16 Ks[64 * 104];       // [s][d] pad 96->104
    __shared__ bf16 Vs[96 * 72];        // [d][s] pad 64->72
    __shared__ bf16 Ps[4][32][72];      // per-wave P[q][s]
    int t = threadIdx.x, lane = t & 63, wave = t >> 6;
    int quad = lane >> 4, l16 = lane & 15;
    int bh = blockIdx.x % BH_;
    int ch = (S_ / 128 - 1) - blockIdx.x / BH_;   // heavy chunks first
    int b = bh / H_, h = bh % H_;
    int q0 = ch * 128;
    int qw = q0 + wave * 32;
    int qg0 = qw + l16, qg1 = qw + 16 + l16;

    const char* KbaseB = (const char*)(Kg + (size_t)(b * S_) * HD_ + h * D_);
    const char* VbaseB = (const char*)(VT + (size_t)(bh * D_) * S_);

    int krow[4], koff[4], vrow[4], voff[4];
    #pragma unroll
    for (int i = 0; i < 4; ++i) {
        int c = i * 256 + t;
        krow[i] = c / 13; koff[i] = (c % 13) * 16;
        vrow[i] = c / 9;  int cc = c % 9; voff[i] = ((cc == 8) ? 7 : cc) * 16;
    }

    const bf16* qrow0 = Q + (size_t)(b * S_ + qw + l16) * HD_ + h * D_;
    const bf16* qrow1 = qrow0 + (size_t)16 * HD_;
    bf16x8 qf0[3], qf1[3];
    #pragma unroll
    for (int c = 0; c < 3; ++c) {
        qf0[c] = *(const bf16x8*)(qrow0 + c * 32 + quad * 8);
        qf1[c] = *(const bf16x8*)(qrow1 + c * 32 + quad * 8);
    }

    f32x4 o0[6], o1[6];
    #pragma unroll
    for (int u = 0; u < 6; ++u) { o0[u] = (f32x4){0.f,0.f,0.f,0.f}; o1[u] = (f32x4){0.f,0.f,0.f,0.f}; }
    float ls0 = 0.f, ls1 = 0.f;
    const float K2 = 0.10206207261596575f * 1.4426950408889634f;  // scale*log2(e)
    int nk = q0 + 128;

    for (int kb = 0; kb < nk; kb += 64) {
        __syncthreads();
        const char* kg = KbaseB + (size_t)kb * (HD_ * 2);
        #pragma unroll
        for (int i = 0; i < 3; ++i)
            gl2lds16(kg + (size_t)krow[i] * (HD_ * 2) + koff[i], (char*)Ks + i * 4096 + t * 16);
        if (t < 64)
            gl2lds16(kg + (size_t)krow[3] * (HD_ * 2) + koff[3], (char*)Ks + 12288 + t * 16);
        #pragma unroll
        for (int i = 0; i < 4; ++i)
            if (i < 3 || t < 96)
                gl2lds16(VbaseB + (size_t)vrow[i] * (S_ * 2) + (size_t)kb * 2 + voff[i],
                         (char*)Vs + i * 4096 + t * 16);
        __syncthreads();

        // S^T for both q-groups, sharing each kf fragment
        f32x4 s0[4], s1[4];
        #pragma unroll
        for (int u = 0; u < 4; ++u) { s0[u] = (f32x4){0.f,0.f,0.f,0.f}; s1[u] = (f32x4){0.f,0.f,0.f,0.f}; }
        #pragma unroll
        for (int c = 0; c < 3; ++c)
            #pragma unroll
            for (int u = 0; u < 4; ++u) {
                bf16x8 kf = *(const bf16x8*)(Ks + (u * 16 + l16) * 104 + c * 32 + quad * 8);
                s0[u] = __builtin_amdgcn_mfma_f32_16x16x32_bf16(kf, qf0[c], s0[u], 0, 0, 0);
                s1[u] = __builtin_amdgcn_mfma_f32_16x16x32_bf16(kf, qf1[c], s1[u], 0, 0, 0);
            }

        #pragma unroll
        for (int u = 0; u < 4; ++u) {
            bf16x4 pv0, pv1;
            #pragma unroll
            for (int r = 0; r < 4; ++r) {
                int sidx = kb + u * 16 + quad * 4 + r;
                float e0 = __builtin_exp2f(s0[u][r] * K2);
                float e1 = __builtin_exp2f(s1[u][r] * K2);
                e0 = (sidx <= qg0) ? e0 : 0.f;
                e1 = (sidx <= qg1) ? e1 : 0.f;
                ls0 += e0; ls1 += e1;
                pv0[r] = (bf16)e0; pv1[r] = (bf16)e1;
            }
            *(bf16x4*)(&Ps[wave][l16][u * 16 + quad * 4])      = pv0;
            *(bf16x4*)(&Ps[wave][16 + l16][u * 16 + quad * 4]) = pv1;
        }
        asm volatile("s_waitcnt lgkmcnt(0)" ::: "memory");

        bf16x8 p00 = *(const bf16x8*)(&Ps[wave][l16][quad * 8]);
        bf16x8 p01 = *(const bf16x8*)(&Ps[wave][l16][32 + quad * 8]);
        bf16x8 p10 = *(const bf16x8*)(&Ps[wave][16 + l16][quad * 8]);
        bf16x8 p11 = *(const bf16x8*)(&Ps[wave][16 + l16][32 + quad * 8]);
        #pragma unroll
        for (int u = 0; u < 6; ++u) {
            bf16x8 v0 = *(const bf16x8*)(Vs + (u * 16 + l16) * 72 + quad * 8);
            o0[u] = __builtin_amdgcn_mfma_f32_16x16x32_bf16(v0, p00, o0[u], 0, 0, 0);
            o1[u] = __builtin_amdgcn_mfma_f32_16x16x32_bf16(v0, p10, o1[u], 0, 0, 0);
            bf16x8 v1 = *(const bf16x8*)(Vs + (u * 16 + l16) * 72 + 32 + quad * 8);
            o0[u] = __builtin_amdgcn_mfma_f32_16x16x32_bf16(v1, p01, o0[u], 0, 0, 0);
            o1[u] = __builtin_amdgcn_mfma_f32_16x16x32_bf16(v1, p11, o1[u], 0, 0, 0);
        }
    }

    ls0 += __shfl_xor(ls0, 16, 64); ls0 += __shfl_xor(ls0, 32, 64);
    ls1 += __shfl_xor(ls1, 16, 64); ls1 += __shfl_xor(ls1, 32, 64);
    float inv0 = 1.0f / ls0, inv1 = 1.0f / ls1;

    bf16* crow0 = ctx + (size_t)(b * S_ + qw + l16) * HD_ + h * D_;
    bf16* crow1 = crow0 + (size_t)16 * HD_;
    #pragma unroll
    for (int u = 0; u < 6; ++u) {
        bf16x4 a, c;
        #pragma unroll
        for (int r = 0; r < 4; ++r) { a[r] = (bf16)(o0[u][r] * inv0); c[r] = (bf16)(o1[u][r] * inv1); }
        *(bf16x4*)(crow0 + u * 16 + quad * 4) = a;
        *(bf16x4*)(crow1 + u * 16 + quad * 4) = c;
    }
}

// ---------------------------------------------------------------- launch
extern "C" void kernel_launch(void* const* d_in, const int* in_sizes, int n_in,
                              void* d_out, int out_size, void* d_ws, size_t ws_size,
                              hipStream_t stream) {
    const float* logits = (const float*)d_in[0];
    const float* Wq = (const float*)d_in[1];
    const float* bq = (const float*)d_in[2];
    const float* Wk = (const float*)d_in[3];
    const float* bk = (const float*)d_in[4];
    const float* Wv = (const float*)d_in[5];
    const float* bv = (const float*)d_in[6];
    const float* Wo = (const float*)d_in[7];
    const float* bo = (const float*)d_in[8];
    float* out = (float*)d_out;

    char* ws = (char*)d_ws;
    size_t off = 0;
    auto alloc = [&](size_t bytes) { char* p = ws + off; off += (bytes + 255) & ~(size_t)255; return p; };
    bf16* Xbf = (bf16*)alloc((size_t)M_ * E_ * 2);
    bf16* WqT = (bf16*)alloc((size_t)E_ * HD_ * 2);
    bf16* WkT = (bf16*)alloc((size_t)E_ * HD_ * 2);
    bf16* WvT = (bf16*)alloc((size_t)E_ * HD_ * 2);
    bf16* WoT = (bf16*)alloc((size_t)HD_ * E_ * 2);
    bf16* qb  = (bf16*)alloc((size_t)M_ * HD_ * 2);
    bf16* kb  = (bf16*)alloc((size_t)M_ * HD_ * 2);
    bf16* VT  = (bf16*)alloc((size_t)M_ * HD_ * 2);
    float2* ctab = (float2*)alloc((size_t)S_ * 48 * 8);
    bf16* ctx = Xbf;  // reuse: logits-bf16 dead after QKV GEMMs

    hipLaunchKernelGGL(prep_k, dim3(CAST_B_ + TAB_B_ + 4 * 1296), dim3(256), 0, stream,
                       logits, Xbf, ctab, Wq, Wk, Wv, Wo, WqT, WkT, WvT, WoT);
    hipLaunchKernelGGL(gemm_qkv_k, dim3(M_ / 128, 27), dim3(256), 0, stream,
                       Xbf, WqT, WkT, WvT, bq, bk, bv, qb, kb, VT, ctab);
    hipLaunchKernelGGL(flash4_k, dim3(BH_ * (S_ / 128)), dim3(256), 0, stream, qb, kb, VT, ctx);
    hipLaunchKernelGGL(gemm_out_k, dim3(M_ / 128, 1152 / 128), dim3(256), 0, stream, ctx, WoT, bo, out);
}